// Round 13
// baseline (74.000 us; speedup 1.0000x reference)
//
#include <hip/hip_runtime.h>

typedef float v2f __attribute__((ext_vector_type(2)));

namespace {
constexpr int kB = 16384;
constexpr int kC = 1000;
constexpr int kNElem = kB * kC;           // 16,384,000
constexpr int kNV4 = kNElem / 4;          // 4,096,000 float4 chunks
constexpr int kV4PerRow = kC / 4;         // 250
constexpr int kBlocks = 1280;             // R10-proven: 5 blk/CU, n = 12..13
constexpr int kThreads = 256;
constexpr int kS = kBlocks * kThreads;    // 327,680 (grid stride in float4s)
}

// ws: float pf[10][kBlocks] — per-block hinge-sum partials acc_j (c_0 = 0 -> T)
//     u32   pu[10][kBlocks] — per-block bin-count partials N_k
//     u32   ctr              — last-block-done counter (memset to 0 per call)
// All cross-block traffic uses AGENT-scope atomics (per-XCD L2s not coherent;
// also guards against stale L2 lines from the previous graph replay).
// finalize (f64): cnt_j = sum_{k>=j} N_k; cum_j = acc_j - c_j*(N - cnt_j);
//                 S_k = cum_k - cum_{k+1}; loss = (1/n) sum_{N_k>0} S_k/N_k.

__device__ __forceinline__ void ghmc_elem(float L, float& bce, unsigned& bin)
{
    const float kLn2   = 0.6931471805599453f;
    const float kNRLn2 = -1.4426950408889634f;
    const float en  = __builtin_amdgcn_exp2f(kNRLn2 * fabsf(L));  // e^{-|L|}
    const float den = 1.f + en;
    const float lg  = __builtin_amdgcn_logf(den);                 // log2(den)
    const float r   = __builtin_amdgcn_rcpf(den);
    bce = fmaf(lg, kLn2, fmaxf(L, 0.f));                          // softplus(L)
    unsigned babs = (unsigned)(10.f * r);
    babs = babs > 9u ? 9u : babs;                                 // in [5,9]
    bin = (L >= 0.f) ? babs : 9u - babs;
}

// one float4 chunk (4 consecutive elements of one row) + rare target correction.
__device__ __forceinline__ void proc4(const float4 v, int dt,
    v2f& a01, v2f& a23, v2f& a45, v2f& a67, v2f& a89,
    unsigned long long& hcnt,
    const v2f C01, const v2f C23, const v2f C45, const v2f C67, const v2f C89)
{
    const float lv[4] = {v.x, v.y, v.z, v.w};
    #pragma unroll
    for (int e = 0; e < 4; ++e) {
        float bce; unsigned bin;
        ghmc_elem(lv[e], bce, bin);
        hcnt += 1ull << (6u * bin);
        const v2f b2 = {bce, bce};
        a01 += __builtin_elementwise_max(b2, C01);
        a23 += __builtin_elementwise_max(b2, C23);
        a45 += __builtin_elementwise_max(b2, C45);
        a67 += __builtin_elementwise_max(b2, C67);
        a89 += __builtin_elementwise_max(b2, C89);
    }
    if (__builtin_expect((unsigned)dt < 4u, 0)) {
        float L = v.x;
        L = (dt == 1) ? v.y : L;
        L = (dt == 2) ? v.z : L;
        L = (dt == 3) ? v.w : L;
        float bn_; unsigned bnb;
        ghmc_elem(L, bn_, bnb);                 // what the main path added
        const float bt_ = bn_ - L;              // softplus(-L) = softplus(L) - L
        const unsigned babs = (bnb >= 5u) ? bnb : 9u - bnb;   // |L|-bin in [5,9]
        const unsigned btb  = (L <= 0.f) ? babs : 9u - babs;
        hcnt += (1ull << (6u * btb)) - (1ull << (6u * bnb));
        const v2f bn2 = {bn_, bn_}, bt2 = {bt_, bt_};
        a01 += __builtin_elementwise_max(bt2, C01) - __builtin_elementwise_max(bn2, C01);
        a23 += __builtin_elementwise_max(bt2, C23) - __builtin_elementwise_max(bn2, C23);
        a45 += __builtin_elementwise_max(bt2, C45) - __builtin_elementwise_max(bn2, C45);
        a67 += __builtin_elementwise_max(bt2, C67) - __builtin_elementwise_max(bn2, C67);
        a89 += __builtin_elementwise_max(bt2, C89) - __builtin_elementwise_max(bn2, C89);
    }
}

__global__ __launch_bounds__(kThreads) void ghmc_main(
    const float* __restrict__ logits,
    const int* __restrict__ tgt,
    float* __restrict__ pf,
    unsigned* __restrict__ pu,
    unsigned* __restrict__ ctr,
    float* __restrict__ out)
{
    const v2f C01 = {0.0f,        0.10536052f};
    const v2f C23 = {0.22314355f, 0.35667494f};
    const v2f C45 = {0.51082562f, 0.69314718f};
    const v2f C67 = {0.91629073f, 1.20397280f};
    const v2f C89 = {1.60943791f, 2.30258509f};

    v2f a01 = {0.f,0.f}, a23 = {0.f,0.f}, a45 = {0.f,0.f},
        a67 = {0.f,0.f}, a89 = {0.f,0.f};
    unsigned long long hcnt = 0ull;

    const int gid = blockIdx.x * blockDim.x + threadIdx.x;
    const int n = (kNV4 - 1 - gid) / kS + 1;      // 12 or 13 iterations
    const float4* __restrict__ Lp = reinterpret_cast<const float4*>(logits);

    auto ld = [&](int idx) {                      // clamped (over-read harmless)
        idx = idx < kNV4 ? idx : kNV4 - 1;
        return Lp[idx];
    };
    auto dtf = [&](const float4*, int idx) {
        const int row = idx / kV4PerRow;          // magic-mul div (const 250)
        return tgt[row] - (idx - row * kV4PerRow) * 4;
    };

    // R10's modulo-scheduled pipeline: depth 3-4, unroll-by-4, named cyclic regs.
    int i = gid;
    float4 q0 = ld(i), q1 = ld(i + kS), q2 = ld(i + 2 * kS);

    int k = 0;
    for (; k + 4 <= n; k += 4) {
        float4 q3 = ld(i + 3 * kS);
        proc4(q0, dtf(Lp, i),          a01, a23, a45, a67, a89, hcnt, C01, C23, C45, C67, C89);
        q0 = ld(i + 4 * kS);
        proc4(q1, dtf(Lp, i + kS),     a01, a23, a45, a67, a89, hcnt, C01, C23, C45, C67, C89);
        q1 = ld(i + 5 * kS);
        proc4(q2, dtf(Lp, i + 2 * kS), a01, a23, a45, a67, a89, hcnt, C01, C23, C45, C67, C89);
        q2 = ld(i + 6 * kS);
        proc4(q3, dtf(Lp, i + 3 * kS), a01, a23, a45, a67, a89, hcnt, C01, C23, C45, C67, C89);
        i += 4 * kS;
    }
    if (k < n) {                                  // tail: 0 or 1 iteration
        proc4(q0, dtf(Lp, i), a01, a23, a45, a67, a89, hcnt, C01, C23, C45, C67, C89);
    }

    // expand 6-bit fields -> two u64 with 12-bit fields (wave sum <= 52*64 = 3328 < 4096)
    unsigned long long lo = 0ull, hi = 0ull;
    #pragma unroll
    for (int j = 0; j < 5; ++j) {
        lo += ((hcnt >> (6 * j))       & 63ull) << (12 * j);
        hi += ((hcnt >> (6 * (j + 5))) & 63ull) << (12 * j);
    }
    float r10[10] = {a01.x, a01.y, a23.x, a23.y, a45.x, a45.y, a67.x, a67.y, a89.x, a89.y};
    #pragma unroll
    for (int off = 32; off > 0; off >>= 1) {
        #pragma unroll
        for (int j = 0; j < 10; ++j) r10[j] += __shfl_down(r10[j], off);
        lo += __shfl_down(lo, off);
        hi += __shfl_down(hi, off);
    }

    __shared__ float              sf[4][10];
    __shared__ unsigned long long sc[4][2];
    const int wave = threadIdx.x >> 6;
    const int lane = threadIdx.x & 63;
    if (lane == 0) {
        #pragma unroll
        for (int j = 0; j < 10; ++j) sf[wave][j] = r10[j];
        sc[wave][0] = lo; sc[wave][1] = hi;
    }
    __syncthreads();

    // publish per-block partials with AGENT-scope atomic stores (cross-XCD safe)
    const int t = threadIdx.x;
    if (t < 10) {
        const float v = sf[0][t] + sf[1][t] + sf[2][t] + sf[3][t];
        __hip_atomic_store(&pf[t * kBlocks + blockIdx.x], v,
                           __ATOMIC_RELAXED, __HIP_MEMORY_SCOPE_AGENT);
    } else if (t < 20) {
        const int b = t - 10;
        const int half = (b < 5) ? 0 : 1;
        const int sh = 12 * (b < 5 ? b : b - 5);
        unsigned s = 0;
        #pragma unroll
        for (int w = 0; w < 4; ++w) s += (unsigned)((sc[w][half] >> sh) & 4095ull);
        __hip_atomic_store(&pu[b * kBlocks + blockIdx.x], s,
                           __ATOMIC_RELAXED, __HIP_MEMORY_SCOPE_AGENT);
    }
    __syncthreads();   // HIP semantics: drains vmcnt -> this block's stores complete

    __shared__ int s_last;
    if (t == 0) {
        const unsigned prev = __hip_atomic_fetch_add(
            ctr, 1u, __ATOMIC_ACQ_REL, __HIP_MEMORY_SCOPE_AGENT);
        s_last = (prev == (unsigned)(kBlocks - 1));
    }
    __syncthreads();
    if (!s_last) return;

    // ---- LAST BLOCK: fused reduction + finalize (deterministic order) ----
    __shared__ double             rF[10];
    __shared__ unsigned long long rC[10];
    #pragma unroll
    for (int s = wave; s < 10; s += 4) {          // wave handles slots s, s+4, s+8
        double fs = 0.0;
        unsigned long long cs = 0ull;
        for (int b = lane; b < kBlocks; b += 64) {  // coalesced, independent loads
            fs += (double)__hip_atomic_load(&pf[s * kBlocks + b],
                                            __ATOMIC_RELAXED, __HIP_MEMORY_SCOPE_AGENT);
            cs += __hip_atomic_load(&pu[s * kBlocks + b],
                                    __ATOMIC_RELAXED, __HIP_MEMORY_SCOPE_AGENT);
        }
        #pragma unroll
        for (int off = 32; off > 0; off >>= 1) {
            fs += __shfl_down(fs, off);
            cs += __shfl_down(cs, off);
        }
        if (lane == 0) { rF[s] = fs; rC[s] = cs; }
    }
    __syncthreads();

    if (t == 0) {
        const double cj[10] = {0.0,
            0.10536051565782630, 0.22314355131420976, 0.35667494393873245,
            0.51082562376599072, 0.69314718055994531, 0.91629073187415511,
            1.20397280432593600, 1.60943791243410040, 2.30258509299404570};
        double N[10], cnt[11], cum[11];
        for (int j = 0; j < 10; ++j) N[j] = (double)rC[j];
        cnt[10] = 0.0;
        for (int j = 9; j >= 0; --j) cnt[j] = cnt[j + 1] + N[j];
        cum[10] = 0.0;
        cum[0] = rF[0];                                   // T (c=0 hinge is exact)
        for (int j = 1; j <= 9; ++j)
            cum[j] = rF[j] - cj[j] * ((double)kNElem - cnt[j]);
        double loss = 0.0, nn = 0.0;
        for (int j = 0; j < 10; ++j) {
            if (N[j] > 0.0) { nn += 1.0; loss += (cum[j] - cum[j + 1]) / N[j]; }
        }
        out[0] = (float)(loss / (nn > 1.0 ? nn : 1.0));
    }
}

extern "C" void kernel_launch(void* const* d_in, const int* in_sizes, int n_in,
                              void* d_out, int out_size, void* d_ws, size_t ws_size,
                              hipStream_t stream)
{
    const float* logits = (const float*)d_in[0];
    const int*   tgt    = (const int*)d_in[1];
    float*    pf  = (float*)d_ws;                                   // 10 x 1280 f32
    unsigned* pu  = (unsigned*)((char*)d_ws + 10 * kBlocks * 4);    // 10 x 1280 u32
    unsigned* ctr = (unsigned*)((char*)d_ws + 20 * kBlocks * 4);    // 1 u32
    hipMemsetAsync(ctr, 0, 4, stream);
    ghmc_main<<<kBlocks, kThreads, 0, stream>>>(logits, tgt, pf, pu, ctr,
                                                (float*)d_out);
}

// Round 14
// 53.199 us; speedup vs baseline: 1.3910x; 1.3910x over previous
//
#include <hip/hip_runtime.h>

typedef float v2f __attribute__((ext_vector_type(2)));

namespace {
constexpr int kB = 16384;
constexpr int kC = 1000;
constexpr int kNElem = kB * kC;           // 16,384,000
constexpr int kNV4 = kNElem / 4;          // 4,096,000 float4 chunks
constexpr int kV4PerRow = kC / 4;         // 250
constexpr int kBlocks = 1280;             // R10-proven: 5 blk/CU, n = 12..13
constexpr int kThreads = 256;
constexpr int kS = kBlocks * kThreads;    // 327,680 (grid stride in float4s)
}

// ws: float pf[10][kBlocks] — per-block hinge-sum partials acc_j (c_0 = 0 -> T)
//     u32   pu[10][kBlocks] — per-block bin-count partials N_k
//     u32   ctr              — last-block-done counter (memset to 0 per call)
// Cross-block traffic: RELAXED agent-scope atomics ONLY. R13 lesson: acq_rel
// at agent scope emits buffer_wbl2+buffer_inv per block -> 1280 L2 nukes ->
// 2.5x slowdown. Relaxed agent ops are plain coherence-point accesses; the
// __syncthreads() vmcnt-drain before the counter RMW provides the ordering.
// finalize (f64): cnt_j = sum_{k>=j} N_k; cum_j = acc_j - c_j*(N - cnt_j);
//                 S_k = cum_k - cum_{k+1}; loss = (1/n) sum_{N_k>0} S_k/N_k.

__device__ __forceinline__ void ghmc_elem(float L, float& bce, unsigned& bin)
{
    const float kLn2   = 0.6931471805599453f;
    const float kNRLn2 = -1.4426950408889634f;
    const float en  = __builtin_amdgcn_exp2f(kNRLn2 * fabsf(L));  // e^{-|L|}
    const float den = 1.f + en;
    const float lg  = __builtin_amdgcn_logf(den);                 // log2(den)
    const float r   = __builtin_amdgcn_rcpf(den);
    bce = fmaf(lg, kLn2, fmaxf(L, 0.f));                          // softplus(L)
    unsigned babs = (unsigned)(10.f * r);
    babs = babs > 9u ? 9u : babs;                                 // in [5,9]
    bin = (L >= 0.f) ? babs : 9u - babs;
}

// one float4 chunk (4 consecutive elements of one row) + rare target correction.
__device__ __forceinline__ void proc4(const float4 v, int dt,
    v2f& a01, v2f& a23, v2f& a45, v2f& a67, v2f& a89,
    unsigned long long& hcnt,
    const v2f C01, const v2f C23, const v2f C45, const v2f C67, const v2f C89)
{
    const float lv[4] = {v.x, v.y, v.z, v.w};
    #pragma unroll
    for (int e = 0; e < 4; ++e) {
        float bce; unsigned bin;
        ghmc_elem(lv[e], bce, bin);
        hcnt += 1ull << (6u * bin);
        const v2f b2 = {bce, bce};
        a01 += __builtin_elementwise_max(b2, C01);
        a23 += __builtin_elementwise_max(b2, C23);
        a45 += __builtin_elementwise_max(b2, C45);
        a67 += __builtin_elementwise_max(b2, C67);
        a89 += __builtin_elementwise_max(b2, C89);
    }
    if (__builtin_expect((unsigned)dt < 4u, 0)) {
        float L = v.x;
        L = (dt == 1) ? v.y : L;
        L = (dt == 2) ? v.z : L;
        L = (dt == 3) ? v.w : L;
        float bn_; unsigned bnb;
        ghmc_elem(L, bn_, bnb);                 // what the main path added
        const float bt_ = bn_ - L;              // softplus(-L) = softplus(L) - L
        const unsigned babs = (bnb >= 5u) ? bnb : 9u - bnb;   // |L|-bin in [5,9]
        const unsigned btb  = (L <= 0.f) ? babs : 9u - babs;
        hcnt += (1ull << (6u * btb)) - (1ull << (6u * bnb));
        const v2f bn2 = {bn_, bn_}, bt2 = {bt_, bt_};
        a01 += __builtin_elementwise_max(bt2, C01) - __builtin_elementwise_max(bn2, C01);
        a23 += __builtin_elementwise_max(bt2, C23) - __builtin_elementwise_max(bn2, C23);
        a45 += __builtin_elementwise_max(bt2, C45) - __builtin_elementwise_max(bn2, C45);
        a67 += __builtin_elementwise_max(bt2, C67) - __builtin_elementwise_max(bn2, C67);
        a89 += __builtin_elementwise_max(bt2, C89) - __builtin_elementwise_max(bn2, C89);
    }
}

__global__ __launch_bounds__(kThreads) void ghmc_main(
    const float* __restrict__ logits,
    const int* __restrict__ tgt,
    float* __restrict__ pf,
    unsigned* __restrict__ pu,
    unsigned* __restrict__ ctr,
    float* __restrict__ out)
{
    const v2f C01 = {0.0f,        0.10536052f};
    const v2f C23 = {0.22314355f, 0.35667494f};
    const v2f C45 = {0.51082562f, 0.69314718f};
    const v2f C67 = {0.91629073f, 1.20397280f};
    const v2f C89 = {1.60943791f, 2.30258509f};

    v2f a01 = {0.f,0.f}, a23 = {0.f,0.f}, a45 = {0.f,0.f},
        a67 = {0.f,0.f}, a89 = {0.f,0.f};
    unsigned long long hcnt = 0ull;

    const int gid = blockIdx.x * blockDim.x + threadIdx.x;
    const int n = (kNV4 - 1 - gid) / kS + 1;      // 12 or 13 iterations
    const float4* __restrict__ Lp = reinterpret_cast<const float4*>(logits);

    auto ld = [&](int idx) {                      // clamped (over-read harmless)
        idx = idx < kNV4 ? idx : kNV4 - 1;
        return Lp[idx];
    };
    auto dtf = [&](int idx) {
        const int row = idx / kV4PerRow;          // magic-mul div (const 250)
        return tgt[row] - (idx - row * kV4PerRow) * 4;
    };

    // R10's modulo-scheduled pipeline: depth 3-4, unroll-by-4, named cyclic regs.
    int i = gid;
    float4 q0 = ld(i), q1 = ld(i + kS), q2 = ld(i + 2 * kS);

    int k = 0;
    for (; k + 4 <= n; k += 4) {
        float4 q3 = ld(i + 3 * kS);
        proc4(q0, dtf(i),          a01, a23, a45, a67, a89, hcnt, C01, C23, C45, C67, C89);
        q0 = ld(i + 4 * kS);
        proc4(q1, dtf(i + kS),     a01, a23, a45, a67, a89, hcnt, C01, C23, C45, C67, C89);
        q1 = ld(i + 5 * kS);
        proc4(q2, dtf(i + 2 * kS), a01, a23, a45, a67, a89, hcnt, C01, C23, C45, C67, C89);
        q2 = ld(i + 6 * kS);
        proc4(q3, dtf(i + 3 * kS), a01, a23, a45, a67, a89, hcnt, C01, C23, C45, C67, C89);
        i += 4 * kS;
    }
    if (k < n) {                                  // tail: 0 or 1 iteration
        proc4(q0, dtf(i), a01, a23, a45, a67, a89, hcnt, C01, C23, C45, C67, C89);
    }

    // expand 6-bit fields -> two u64 with 12-bit fields (wave sum <= 52*64 = 3328 < 4096)
    unsigned long long lo = 0ull, hi = 0ull;
    #pragma unroll
    for (int j = 0; j < 5; ++j) {
        lo += ((hcnt >> (6 * j))       & 63ull) << (12 * j);
        hi += ((hcnt >> (6 * (j + 5))) & 63ull) << (12 * j);
    }
    float r10[10] = {a01.x, a01.y, a23.x, a23.y, a45.x, a45.y, a67.x, a67.y, a89.x, a89.y};
    #pragma unroll
    for (int off = 32; off > 0; off >>= 1) {
        #pragma unroll
        for (int j = 0; j < 10; ++j) r10[j] += __shfl_down(r10[j], off);
        lo += __shfl_down(lo, off);
        hi += __shfl_down(hi, off);
    }

    __shared__ float              sf[4][10];
    __shared__ unsigned long long sc[4][2];
    const int wave = threadIdx.x >> 6;
    const int lane = threadIdx.x & 63;
    if (lane == 0) {
        #pragma unroll
        for (int j = 0; j < 10; ++j) sf[wave][j] = r10[j];
        sc[wave][0] = lo; sc[wave][1] = hi;
    }
    __syncthreads();

    // publish per-block partials: RELAXED agent-scope atomic stores
    // (write-through past the non-coherent per-XCD L2; no cache maintenance)
    const int t = threadIdx.x;
    if (t < 10) {
        const float v = sf[0][t] + sf[1][t] + sf[2][t] + sf[3][t];
        __hip_atomic_store(&pf[t * kBlocks + blockIdx.x], v,
                           __ATOMIC_RELAXED, __HIP_MEMORY_SCOPE_AGENT);
    } else if (t < 20) {
        const int b = t - 10;
        const int half = (b < 5) ? 0 : 1;
        const int sh = 12 * (b < 5 ? b : b - 5);
        unsigned s = 0;
        #pragma unroll
        for (int w = 0; w < 4; ++w) s += (unsigned)((sc[w][half] >> sh) & 4095ull);
        __hip_atomic_store(&pu[b * kBlocks + blockIdx.x], s,
                           __ATOMIC_RELAXED, __HIP_MEMORY_SCOPE_AGENT);
    }
    __syncthreads();   // drains vmcnt -> this block's stores have completed/acked

    __shared__ int s_last;
    if (t == 0) {
        // RELAXED RMW at the coherence point — NO wbl2/inv (the R13 poison)
        const unsigned prev = __hip_atomic_fetch_add(
            ctr, 1u, __ATOMIC_RELAXED, __HIP_MEMORY_SCOPE_AGENT);
        s_last = (prev == (unsigned)(kBlocks - 1));
    }
    __syncthreads();
    if (!s_last) return;

    // ---- LAST BLOCK: fused reduction + finalize (deterministic order) ----
    __shared__ double             rF[10];
    __shared__ unsigned long long rC[10];
    #pragma unroll
    for (int s = wave; s < 10; s += 4) {          // wave handles slots s, s+4, s+8
        double fs = 0.0;
        unsigned long long cs = 0ull;
        for (int b = lane; b < kBlocks; b += 64) {  // coalesced, independent loads
            fs += (double)__hip_atomic_load(&pf[s * kBlocks + b],
                                            __ATOMIC_RELAXED, __HIP_MEMORY_SCOPE_AGENT);
            cs += __hip_atomic_load(&pu[s * kBlocks + b],
                                    __ATOMIC_RELAXED, __HIP_MEMORY_SCOPE_AGENT);
        }
        #pragma unroll
        for (int off = 32; off > 0; off >>= 1) {
            fs += __shfl_down(fs, off);
            cs += __shfl_down(cs, off);
        }
        if (lane == 0) { rF[s] = fs; rC[s] = cs; }
    }
    __syncthreads();

    if (t == 0) {
        const double cj[10] = {0.0,
            0.10536051565782630, 0.22314355131420976, 0.35667494393873245,
            0.51082562376599072, 0.69314718055994531, 0.91629073187415511,
            1.20397280432593600, 1.60943791243410040, 2.30258509299404570};
        double N[10], cnt[11], cum[11];
        for (int j = 0; j < 10; ++j) N[j] = (double)rC[j];
        cnt[10] = 0.0;
        for (int j = 9; j >= 0; --j) cnt[j] = cnt[j + 1] + N[j];
        cum[10] = 0.0;
        cum[0] = rF[0];                                   // T (c=0 hinge is exact)
        for (int j = 1; j <= 9; ++j)
            cum[j] = rF[j] - cj[j] * ((double)kNElem - cnt[j]);
        double loss = 0.0, nn = 0.0;
        for (int j = 0; j < 10; ++j) {
            if (N[j] > 0.0) { nn += 1.0; loss += (cum[j] - cum[j + 1]) / N[j]; }
        }
        out[0] = (float)(loss / (nn > 1.0 ? nn : 1.0));
    }
}

extern "C" void kernel_launch(void* const* d_in, const int* in_sizes, int n_in,
                              void* d_out, int out_size, void* d_ws, size_t ws_size,
                              hipStream_t stream)
{
    const float* logits = (const float*)d_in[0];
    const int*   tgt    = (const int*)d_in[1];
    float*    pf  = (float*)d_ws;                                   // 10 x 1280 f32
    unsigned* pu  = (unsigned*)((char*)d_ws + 10 * kBlocks * 4);    // 10 x 1280 u32
    unsigned* ctr = (unsigned*)((char*)d_ws + 20 * kBlocks * 4);    // 1 u32
    hipMemsetAsync(ctr, 0, 4, stream);
    ghmc_main<<<kBlocks, kThreads, 0, stream>>>(logits, tgt, pf, pu, ctr,
                                                (float*)d_out);
}

// Round 15
// 52.739 us; speedup vs baseline: 1.4031x; 1.0087x over previous
//
#include <hip/hip_runtime.h>

typedef float v2f __attribute__((ext_vector_type(2)));

namespace {
constexpr int kB = 16384;
constexpr int kC = 1000;
constexpr int kNElem = kB * kC;           // 16,384,000
constexpr int kNV4 = kNElem / 4;          // 4,096,000 float4 chunks
constexpr int kV4PerRow = kC / 4;         // 250
constexpr int kBlocks = 1280;             // R10-proven: 5 blk/CU, n = 12..13
constexpr int kThreads = 256;
constexpr int kS = kBlocks * kThreads;    // 327,680 (grid stride in float4s)
constexpr int kGroups = 40;               // 40 groups x 32 blocks = 1280
constexpr int kCtrStride = 16;            // one cache line per counter (u32s)
}

// ws: float pf[10][kBlocks] — per-block hinge-sum partials acc_j (c_0 = 0 -> T)
//     u32   pu[10][kBlocks] — per-block bin-count partials N_k
//     u32   ctr[41*16]      — two-level done counters, line-padded, memset/call
//
// SESSION CONSTANT (R13/R14): same-address atomic RMWs serialize at ~20-35ns
// each; a 1280-long chain = 25-45us. Two-level topology caps chains at 32/40.
// R13: acq_rel agent RMW adds buffer_wbl2+inv per block -> L2 nukes. RELAXED only.
// finalize (f64): cnt_j = sum_{k>=j} N_k; cum_j = acc_j - c_j*(N - cnt_j);
//                 S_k = cum_k - cum_{k+1}; loss = (1/n) sum_{N_k>0} S_k/N_k.

__device__ __forceinline__ void ghmc_elem(float L, float& bce, unsigned& bin)
{
    const float kLn2   = 0.6931471805599453f;
    const float kNRLn2 = -1.4426950408889634f;
    const float en  = __builtin_amdgcn_exp2f(kNRLn2 * fabsf(L));  // e^{-|L|}
    const float den = 1.f + en;
    const float lg  = __builtin_amdgcn_logf(den);                 // log2(den)
    const float r   = __builtin_amdgcn_rcpf(den);
    bce = fmaf(lg, kLn2, fmaxf(L, 0.f));                          // softplus(L)
    unsigned babs = (unsigned)(10.f * r);
    babs = babs > 9u ? 9u : babs;                                 // in [5,9]
    bin = (L >= 0.f) ? babs : 9u - babs;
}

// one float4 chunk (4 consecutive elements of one row) + rare target correction.
__device__ __forceinline__ void proc4(const float4 v, int dt,
    v2f& a01, v2f& a23, v2f& a45, v2f& a67, v2f& a89,
    unsigned long long& hcnt,
    const v2f C01, const v2f C23, const v2f C45, const v2f C67, const v2f C89)
{
    const float lv[4] = {v.x, v.y, v.z, v.w};
    #pragma unroll
    for (int e = 0; e < 4; ++e) {
        float bce; unsigned bin;
        ghmc_elem(lv[e], bce, bin);
        hcnt += 1ull << (6u * bin);
        const v2f b2 = {bce, bce};
        a01 += __builtin_elementwise_max(b2, C01);
        a23 += __builtin_elementwise_max(b2, C23);
        a45 += __builtin_elementwise_max(b2, C45);
        a67 += __builtin_elementwise_max(b2, C67);
        a89 += __builtin_elementwise_max(b2, C89);
    }
    if (__builtin_expect((unsigned)dt < 4u, 0)) {
        float L = v.x;
        L = (dt == 1) ? v.y : L;
        L = (dt == 2) ? v.z : L;
        L = (dt == 3) ? v.w : L;
        float bn_; unsigned bnb;
        ghmc_elem(L, bn_, bnb);                 // what the main path added
        const float bt_ = bn_ - L;              // softplus(-L) = softplus(L) - L
        const unsigned babs = (bnb >= 5u) ? bnb : 9u - bnb;   // |L|-bin in [5,9]
        const unsigned btb  = (L <= 0.f) ? babs : 9u - babs;
        hcnt += (1ull << (6u * btb)) - (1ull << (6u * bnb));
        const v2f bn2 = {bn_, bn_}, bt2 = {bt_, bt_};
        a01 += __builtin_elementwise_max(bt2, C01) - __builtin_elementwise_max(bn2, C01);
        a23 += __builtin_elementwise_max(bt2, C23) - __builtin_elementwise_max(bn2, C23);
        a45 += __builtin_elementwise_max(bt2, C45) - __builtin_elementwise_max(bn2, C45);
        a67 += __builtin_elementwise_max(bt2, C67) - __builtin_elementwise_max(bn2, C67);
        a89 += __builtin_elementwise_max(bt2, C89) - __builtin_elementwise_max(bn2, C89);
    }
}

__global__ __launch_bounds__(kThreads) void ghmc_main(
    const float* __restrict__ logits,
    const int* __restrict__ tgt,
    float* __restrict__ pf,
    unsigned* __restrict__ pu,
    unsigned* __restrict__ ctr,
    float* __restrict__ out)
{
    const v2f C01 = {0.0f,        0.10536052f};
    const v2f C23 = {0.22314355f, 0.35667494f};
    const v2f C45 = {0.51082562f, 0.69314718f};
    const v2f C67 = {0.91629073f, 1.20397280f};
    const v2f C89 = {1.60943791f, 2.30258509f};

    v2f a01 = {0.f,0.f}, a23 = {0.f,0.f}, a45 = {0.f,0.f},
        a67 = {0.f,0.f}, a89 = {0.f,0.f};
    unsigned long long hcnt = 0ull;

    const int gid = blockIdx.x * blockDim.x + threadIdx.x;
    const int n = (kNV4 - 1 - gid) / kS + 1;      // 12 or 13 iterations
    const float4* __restrict__ Lp = reinterpret_cast<const float4*>(logits);

    auto ld = [&](int idx) {                      // clamped (over-read harmless)
        idx = idx < kNV4 ? idx : kNV4 - 1;
        return Lp[idx];
    };
    auto dtf = [&](int idx) {
        const int row = idx / kV4PerRow;          // magic-mul div (const 250)
        return tgt[row] - (idx - row * kV4PerRow) * 4;
    };

    // R10's modulo-scheduled pipeline: depth 3-4, unroll-by-4, named cyclic regs.
    int i = gid;
    float4 q0 = ld(i), q1 = ld(i + kS), q2 = ld(i + 2 * kS);

    int k = 0;
    for (; k + 4 <= n; k += 4) {
        float4 q3 = ld(i + 3 * kS);
        proc4(q0, dtf(i),          a01, a23, a45, a67, a89, hcnt, C01, C23, C45, C67, C89);
        q0 = ld(i + 4 * kS);
        proc4(q1, dtf(i + kS),     a01, a23, a45, a67, a89, hcnt, C01, C23, C45, C67, C89);
        q1 = ld(i + 5 * kS);
        proc4(q2, dtf(i + 2 * kS), a01, a23, a45, a67, a89, hcnt, C01, C23, C45, C67, C89);
        q2 = ld(i + 6 * kS);
        proc4(q3, dtf(i + 3 * kS), a01, a23, a45, a67, a89, hcnt, C01, C23, C45, C67, C89);
        i += 4 * kS;
    }
    if (k < n) {                                  // tail: 0 or 1 iteration
        proc4(q0, dtf(i), a01, a23, a45, a67, a89, hcnt, C01, C23, C45, C67, C89);
    }

    // expand 6-bit fields -> two u64 with 12-bit fields (wave sum <= 52*64 = 3328 < 4096)
    unsigned long long lo = 0ull, hi = 0ull;
    #pragma unroll
    for (int j = 0; j < 5; ++j) {
        lo += ((hcnt >> (6 * j))       & 63ull) << (12 * j);
        hi += ((hcnt >> (6 * (j + 5))) & 63ull) << (12 * j);
    }
    float r10[10] = {a01.x, a01.y, a23.x, a23.y, a45.x, a45.y, a67.x, a67.y, a89.x, a89.y};
    #pragma unroll
    for (int off = 32; off > 0; off >>= 1) {
        #pragma unroll
        for (int j = 0; j < 10; ++j) r10[j] += __shfl_down(r10[j], off);
        lo += __shfl_down(lo, off);
        hi += __shfl_down(hi, off);
    }

    __shared__ float              sf[4][10];
    __shared__ unsigned long long sc[4][2];
    const int wave = threadIdx.x >> 6;
    const int lane = threadIdx.x & 63;
    if (lane == 0) {
        #pragma unroll
        for (int j = 0; j < 10; ++j) sf[wave][j] = r10[j];
        sc[wave][0] = lo; sc[wave][1] = hi;
    }
    __syncthreads();

    // publish per-block partials: RELAXED agent-scope atomic stores (R14-proven)
    const int t = threadIdx.x;
    if (t < 10) {
        const float v = sf[0][t] + sf[1][t] + sf[2][t] + sf[3][t];
        __hip_atomic_store(&pf[t * kBlocks + blockIdx.x], v,
                           __ATOMIC_RELAXED, __HIP_MEMORY_SCOPE_AGENT);
    } else if (t < 20) {
        const int b = t - 10;
        const int half = (b < 5) ? 0 : 1;
        const int sh = 12 * (b < 5 ? b : b - 5);
        unsigned s = 0;
        #pragma unroll
        for (int w = 0; w < 4; ++w) s += (unsigned)((sc[w][half] >> sh) & 4095ull);
        __hip_atomic_store(&pu[b * kBlocks + blockIdx.x], s,
                           __ATOMIC_RELAXED, __HIP_MEMORY_SCOPE_AGENT);
    }
    __syncthreads();   // drains vmcnt -> this block's stores acked at coherence pt

    // two-level last-block-done: chains capped at 32 (group) and 40 (root)
    __shared__ int s_last;
    if (t == 0) {
        const int g = blockIdx.x >> 5;            // 32 blocks per group
        int last = 0;
        unsigned prev = __hip_atomic_fetch_add(&ctr[g * kCtrStride], 1u,
                                               __ATOMIC_RELAXED,
                                               __HIP_MEMORY_SCOPE_AGENT);
        if (prev == 31u) {                        // group-last
            prev = __hip_atomic_fetch_add(&ctr[kGroups * kCtrStride], 1u,
                                          __ATOMIC_RELAXED,
                                          __HIP_MEMORY_SCOPE_AGENT);
            last = (prev == (unsigned)(kGroups - 1));
        }
        s_last = last;
    }
    __syncthreads();
    if (!s_last) return;

    // ---- GLOBAL-LAST BLOCK: fused reduction + finalize (deterministic) ----
    __shared__ double             rF[10];
    __shared__ unsigned long long rC[10];
    for (int s = wave; s < 10; s += 4) {          // wave w: slots w, w+4, w+8
        double fs = 0.0;
        unsigned long long cs = 0ull;
        for (int b = lane; b < kBlocks; b += 64) {  // coalesced, independent loads
            fs += (double)__hip_atomic_load(&pf[s * kBlocks + b],
                                            __ATOMIC_RELAXED, __HIP_MEMORY_SCOPE_AGENT);
            cs += __hip_atomic_load(&pu[s * kBlocks + b],
                                    __ATOMIC_RELAXED, __HIP_MEMORY_SCOPE_AGENT);
        }
        #pragma unroll
        for (int off = 32; off > 0; off >>= 1) {
            fs += __shfl_down(fs, off);
            cs += __shfl_down(cs, off);
        }
        if (lane == 0) { rF[s] = fs; rC[s] = cs; }
    }
    __syncthreads();

    if (t == 0) {
        const double cj[10] = {0.0,
            0.10536051565782630, 0.22314355131420976, 0.35667494393873245,
            0.51082562376599072, 0.69314718055994531, 0.91629073187415511,
            1.20397280432593600, 1.60943791243410040, 2.30258509299404570};
        double N[10], cnt[11], cum[11];
        for (int j = 0; j < 10; ++j) N[j] = (double)rC[j];
        cnt[10] = 0.0;
        for (int j = 9; j >= 0; --j) cnt[j] = cnt[j + 1] + N[j];
        cum[10] = 0.0;
        cum[0] = rF[0];                                   // T (c=0 hinge is exact)
        for (int j = 1; j <= 9; ++j)
            cum[j] = rF[j] - cj[j] * ((double)kNElem - cnt[j]);
        double loss = 0.0, nn = 0.0;
        for (int j = 0; j < 10; ++j) {
            if (N[j] > 0.0) { nn += 1.0; loss += (cum[j] - cum[j + 1]) / N[j]; }
        }
        out[0] = (float)(loss / (nn > 1.0 ? nn : 1.0));
    }
}

extern "C" void kernel_launch(void* const* d_in, const int* in_sizes, int n_in,
                              void* d_out, int out_size, void* d_ws, size_t ws_size,
                              hipStream_t stream)
{
    const float* logits = (const float*)d_in[0];
    const int*   tgt    = (const int*)d_in[1];
    float*    pf  = (float*)d_ws;                                   // 10 x 1280 f32
    unsigned* pu  = (unsigned*)((char*)d_ws + 10 * kBlocks * 4);    // 10 x 1280 u32
    unsigned* ctr = (unsigned*)((char*)d_ws + 20 * kBlocks * 4);    // 41 x 16 u32
    hipMemsetAsync(ctr, 0, (kGroups + 1) * kCtrStride * 4, stream);
    ghmc_main<<<kBlocks, kThreads, 0, stream>>>(logits, tgt, pf, pu, ctr,
                                                (float*)d_out);
}

// Round 16
// 37.504 us; speedup vs baseline: 1.9731x; 1.4062x over previous
//
#include <hip/hip_runtime.h>

typedef float v2f __attribute__((ext_vector_type(2)));

namespace {
constexpr int kB = 16384;
constexpr int kC = 1000;
constexpr int kNElem = kB * kC;           // 16,384,000
constexpr int kNV4 = kNElem / 4;          // 4,096,000 float4 chunks
constexpr int kV4PerRow = kC / 4;         // 250
constexpr int kBlocks = 1280;             // R10-proven: 5 blk/CU, n = 12..13
constexpr int kThreads = 256;
constexpr int kS = kBlocks * kThreads;    // 327,680 (grid stride in float4s)
constexpr int kGroups = 40;               // 40 groups x 32 blocks = 1280
constexpr int kCtrStride = 16;            // one cache line per counter (u32s)
constexpr int kCols = kBlocks / 64;       // 20 columns per lane per slot
}

// ws: float pf[10][kBlocks] — per-block hinge-sum partials acc_j (c_0 = 0 -> T)
//     u32   pu[10][kBlocks] — per-block bin-count partials N_k
//     u32   ctr[41*16]      — two-level done counters, line-padded, memset/call
//
// SESSION CONSTANTS: (R8) same-line global-atomic chains ~25ns/link -> never
// chain >100; (R13) acq_rel agent RMW emits buffer_wbl2+inv -> L2 nukes, use
// RELAXED only; (R15) agent-scope atomic LOADS are uncached ~350ns -> never
// consume them in a rolled accumulator loop (vmcnt(0)/iter); unroll for MLP.
// finalize (f64): cnt_j = sum_{k>=j} N_k; cum_j = acc_j - c_j*(N - cnt_j);
//                 S_k = cum_k - cum_{k+1}; loss = (1/n) sum_{N_k>0} S_k/N_k.

__device__ __forceinline__ void ghmc_elem(float L, float& bce, unsigned& bin)
{
    const float kLn2   = 0.6931471805599453f;
    const float kNRLn2 = -1.4426950408889634f;
    const float en  = __builtin_amdgcn_exp2f(kNRLn2 * fabsf(L));  // e^{-|L|}
    const float den = 1.f + en;
    const float lg  = __builtin_amdgcn_logf(den);                 // log2(den)
    const float r   = __builtin_amdgcn_rcpf(den);
    bce = fmaf(lg, kLn2, fmaxf(L, 0.f));                          // softplus(L)
    unsigned babs = (unsigned)(10.f * r);
    babs = babs > 9u ? 9u : babs;                                 // in [5,9]
    bin = (L >= 0.f) ? babs : 9u - babs;
}

// one float4 chunk (4 consecutive elements of one row) + rare target correction.
__device__ __forceinline__ void proc4(const float4 v, int dt,
    v2f& a01, v2f& a23, v2f& a45, v2f& a67, v2f& a89,
    unsigned long long& hcnt,
    const v2f C01, const v2f C23, const v2f C45, const v2f C67, const v2f C89)
{
    const float lv[4] = {v.x, v.y, v.z, v.w};
    #pragma unroll
    for (int e = 0; e < 4; ++e) {
        float bce; unsigned bin;
        ghmc_elem(lv[e], bce, bin);
        hcnt += 1ull << (6u * bin);
        const v2f b2 = {bce, bce};
        a01 += __builtin_elementwise_max(b2, C01);
        a23 += __builtin_elementwise_max(b2, C23);
        a45 += __builtin_elementwise_max(b2, C45);
        a67 += __builtin_elementwise_max(b2, C67);
        a89 += __builtin_elementwise_max(b2, C89);
    }
    if (__builtin_expect((unsigned)dt < 4u, 0)) {
        float L = v.x;
        L = (dt == 1) ? v.y : L;
        L = (dt == 2) ? v.z : L;
        L = (dt == 3) ? v.w : L;
        float bn_; unsigned bnb;
        ghmc_elem(L, bn_, bnb);                 // what the main path added
        const float bt_ = bn_ - L;              // softplus(-L) = softplus(L) - L
        const unsigned babs = (bnb >= 5u) ? bnb : 9u - bnb;   // |L|-bin in [5,9]
        const unsigned btb  = (L <= 0.f) ? babs : 9u - babs;
        hcnt += (1ull << (6u * btb)) - (1ull << (6u * bnb));
        const v2f bn2 = {bn_, bn_}, bt2 = {bt_, bt_};
        a01 += __builtin_elementwise_max(bt2, C01) - __builtin_elementwise_max(bn2, C01);
        a23 += __builtin_elementwise_max(bt2, C23) - __builtin_elementwise_max(bn2, C23);
        a45 += __builtin_elementwise_max(bt2, C45) - __builtin_elementwise_max(bn2, C45);
        a67 += __builtin_elementwise_max(bt2, C67) - __builtin_elementwise_max(bn2, C67);
        a89 += __builtin_elementwise_max(bt2, C89) - __builtin_elementwise_max(bn2, C89);
    }
}

__global__ __launch_bounds__(kThreads) void ghmc_main(
    const float* __restrict__ logits,
    const int* __restrict__ tgt,
    float* __restrict__ pf,
    unsigned* __restrict__ pu,
    unsigned* __restrict__ ctr,
    float* __restrict__ out)
{
    const v2f C01 = {0.0f,        0.10536052f};
    const v2f C23 = {0.22314355f, 0.35667494f};
    const v2f C45 = {0.51082562f, 0.69314718f};
    const v2f C67 = {0.91629073f, 1.20397280f};
    const v2f C89 = {1.60943791f, 2.30258509f};

    v2f a01 = {0.f,0.f}, a23 = {0.f,0.f}, a45 = {0.f,0.f},
        a67 = {0.f,0.f}, a89 = {0.f,0.f};
    unsigned long long hcnt = 0ull;

    const int gid = blockIdx.x * blockDim.x + threadIdx.x;
    const int n = (kNV4 - 1 - gid) / kS + 1;      // 12 or 13 iterations
    const float4* __restrict__ Lp = reinterpret_cast<const float4*>(logits);

    auto ld = [&](int idx) {                      // clamped (over-read harmless)
        idx = idx < kNV4 ? idx : kNV4 - 1;
        return Lp[idx];
    };
    auto dtf = [&](int idx) {
        const int row = idx / kV4PerRow;          // magic-mul div (const 250)
        return tgt[row] - (idx - row * kV4PerRow) * 4;
    };

    // R10's modulo-scheduled pipeline: depth 3-4, unroll-by-4, named cyclic regs.
    int i = gid;
    float4 q0 = ld(i), q1 = ld(i + kS), q2 = ld(i + 2 * kS);

    int k = 0;
    for (; k + 4 <= n; k += 4) {
        float4 q3 = ld(i + 3 * kS);
        proc4(q0, dtf(i),          a01, a23, a45, a67, a89, hcnt, C01, C23, C45, C67, C89);
        q0 = ld(i + 4 * kS);
        proc4(q1, dtf(i + kS),     a01, a23, a45, a67, a89, hcnt, C01, C23, C45, C67, C89);
        q1 = ld(i + 5 * kS);
        proc4(q2, dtf(i + 2 * kS), a01, a23, a45, a67, a89, hcnt, C01, C23, C45, C67, C89);
        q2 = ld(i + 6 * kS);
        proc4(q3, dtf(i + 3 * kS), a01, a23, a45, a67, a89, hcnt, C01, C23, C45, C67, C89);
        i += 4 * kS;
    }
    if (k < n) {                                  // tail: 0 or 1 iteration
        proc4(q0, dtf(i), a01, a23, a45, a67, a89, hcnt, C01, C23, C45, C67, C89);
    }

    // expand 6-bit fields -> two u64 with 12-bit fields (wave sum <= 52*64 = 3328 < 4096)
    unsigned long long lo = 0ull, hi = 0ull;
    #pragma unroll
    for (int j = 0; j < 5; ++j) {
        lo += ((hcnt >> (6 * j))       & 63ull) << (12 * j);
        hi += ((hcnt >> (6 * (j + 5))) & 63ull) << (12 * j);
    }
    float r10[10] = {a01.x, a01.y, a23.x, a23.y, a45.x, a45.y, a67.x, a67.y, a89.x, a89.y};
    #pragma unroll
    for (int off = 32; off > 0; off >>= 1) {
        #pragma unroll
        for (int j = 0; j < 10; ++j) r10[j] += __shfl_down(r10[j], off);
        lo += __shfl_down(lo, off);
        hi += __shfl_down(hi, off);
    }

    __shared__ float              sf[4][10];
    __shared__ unsigned long long sc[4][2];
    const int wave = threadIdx.x >> 6;
    const int lane = threadIdx.x & 63;
    if (lane == 0) {
        #pragma unroll
        for (int j = 0; j < 10; ++j) sf[wave][j] = r10[j];
        sc[wave][0] = lo; sc[wave][1] = hi;
    }
    __syncthreads();

    // publish per-block partials: RELAXED agent-scope atomic stores (R14-proven)
    const int t = threadIdx.x;
    if (t < 10) {
        const float v = sf[0][t] + sf[1][t] + sf[2][t] + sf[3][t];
        __hip_atomic_store(&pf[t * kBlocks + blockIdx.x], v,
                           __ATOMIC_RELAXED, __HIP_MEMORY_SCOPE_AGENT);
    } else if (t < 20) {
        const int b = t - 10;
        const int half = (b < 5) ? 0 : 1;
        const int sh = 12 * (b < 5 ? b : b - 5);
        unsigned s = 0;
        #pragma unroll
        for (int w = 0; w < 4; ++w) s += (unsigned)((sc[w][half] >> sh) & 4095ull);
        __hip_atomic_store(&pu[b * kBlocks + blockIdx.x], s,
                           __ATOMIC_RELAXED, __HIP_MEMORY_SCOPE_AGENT);
    }
    __syncthreads();   // drains vmcnt -> this block's stores acked at coherence pt

    // two-level last-block-done: chains capped at 32 (group) and 40 (root)
    __shared__ int s_last;
    if (t == 0) {
        const int g = blockIdx.x >> 5;            // 32 blocks per group
        int last = 0;
        unsigned prev = __hip_atomic_fetch_add(&ctr[g * kCtrStride], 1u,
                                               __ATOMIC_RELAXED,
                                               __HIP_MEMORY_SCOPE_AGENT);
        if (prev == 31u) {                        // group-last
            prev = __hip_atomic_fetch_add(&ctr[kGroups * kCtrStride], 1u,
                                          __ATOMIC_RELAXED,
                                          __HIP_MEMORY_SCOPE_AGENT);
            last = (prev == (unsigned)(kGroups - 1));
        }
        s_last = last;
    }
    __syncthreads();
    if (!s_last) return;

    // ---- GLOBAL-LAST BLOCK: fused reduction, FULLY UNROLLED for MLP ----
    // R15 lesson: rolled loop = 20 serial ~350ns uncached round-trips per slot.
    // Constant-indexed register arrays under #pragma unroll -> 40 loads in
    // flight -> ~2 round trips per slot.
    __shared__ double             rF[10];
    __shared__ unsigned long long rC[10];
    for (int s = wave; s < 10; s += 4) {          // wave w: slots w, w+4, w+8
        float    fv[kCols];
        unsigned uv[kCols];
        #pragma unroll
        for (int it = 0; it < kCols; ++it) {
            fv[it] = __hip_atomic_load(&pf[s * kBlocks + lane + it * 64],
                                       __ATOMIC_RELAXED, __HIP_MEMORY_SCOPE_AGENT);
            uv[it] = __hip_atomic_load(&pu[s * kBlocks + lane + it * 64],
                                       __ATOMIC_RELAXED, __HIP_MEMORY_SCOPE_AGENT);
        }
        double fs = 0.0;
        unsigned long long cs = 0ull;
        #pragma unroll
        for (int it = 0; it < kCols; ++it) { fs += (double)fv[it]; cs += uv[it]; }
        #pragma unroll
        for (int off = 32; off > 0; off >>= 1) {
            fs += __shfl_down(fs, off);
            cs += __shfl_down(cs, off);
        }
        if (lane == 0) { rF[s] = fs; rC[s] = cs; }
    }
    __syncthreads();

    if (t == 0) {
        const double cj[10] = {0.0,
            0.10536051565782630, 0.22314355131420976, 0.35667494393873245,
            0.51082562376599072, 0.69314718055994531, 0.91629073187415511,
            1.20397280432593600, 1.60943791243410040, 2.30258509299404570};
        double N[10], cnt[11], cum[11];
        for (int j = 0; j < 10; ++j) N[j] = (double)rC[j];
        cnt[10] = 0.0;
        for (int j = 9; j >= 0; --j) cnt[j] = cnt[j + 1] + N[j];
        cum[10] = 0.0;
        cum[0] = rF[0];                                   // T (c=0 hinge is exact)
        for (int j = 1; j <= 9; ++j)
            cum[j] = rF[j] - cj[j] * ((double)kNElem - cnt[j]);
        double loss = 0.0, nn = 0.0;
        for (int j = 0; j < 10; ++j) {
            if (N[j] > 0.0) { nn += 1.0; loss += (cum[j] - cum[j + 1]) / N[j]; }
        }
        out[0] = (float)(loss / (nn > 1.0 ? nn : 1.0));
    }
}

extern "C" void kernel_launch(void* const* d_in, const int* in_sizes, int n_in,
                              void* d_out, int out_size, void* d_ws, size_t ws_size,
                              hipStream_t stream)
{
    const float* logits = (const float*)d_in[0];
    const int*   tgt    = (const int*)d_in[1];
    float*    pf  = (float*)d_ws;                                   // 10 x 1280 f32
    unsigned* pu  = (unsigned*)((char*)d_ws + 10 * kBlocks * 4);    // 10 x 1280 u32
    unsigned* ctr = (unsigned*)((char*)d_ws + 20 * kBlocks * 4);    // 41 x 16 u32
    hipMemsetAsync(ctr, 0, (kGroups + 1) * kCtrStride * 4, stream);
    ghmc_main<<<kBlocks, kThreads, 0, stream>>>(logits, tgt, pf, pu, ctr,
                                                (float*)d_out);
}

// Round 17
// 31.931 us; speedup vs baseline: 2.3175x; 1.1745x over previous
//
#include <hip/hip_runtime.h>

typedef float v2f __attribute__((ext_vector_type(2)));

namespace {
constexpr int kB = 16384;
constexpr int kC = 1000;
constexpr int kNElem = kB * kC;           // 16,384,000
constexpr int kNV4 = kNElem / 4;          // 4,096,000 float4 chunks
constexpr int kV4PerRow = kC / 4;         // 250
constexpr int kBlocks = 1280;             // proven best: 5 blk/CU, n = 12..13
constexpr int kThreads = 256;
constexpr int kS = kBlocks * kThreads;    // 327,680 (grid stride in float4s)
}

// ws: float pf[10][kBlocks] — per-block hinge-sum partials acc_j (c_0 = 0 -> T)
//     u32   pu[10][kBlocks] — per-block bin-count partials N_k
// No global atomics (R8 lesson). finalize (f64): cnt_j = sum_{k>=j} N_k;
// cum_j = acc_j - c_j*(N - cnt_j); S_k = cum_k - cum_{k+1};
// loss = (1/n) sum_{N_k>0} S_k/N_k.
//
// SESSION LEDGER (why this exact shape):
//  - R8:  same-line global-atomic chains ~25ns/link -> plain per-block stores.
//  - R10: modulo-scheduled unroll-4 with NAMED cyclic regs (no rotation copies)
//         beats straight-line (R11), dt-pipelining (R12), and all fusion
//         variants (R13-R16: agent-scope publish + counters cost > 1 launch).
//  - 1280 blocks beats 2000/2048 (R9/R11): longer per-thread runs amortize
//         the pipeline prologue; 2-kernel launch+reduce tail ~6us is minimal.

__device__ __forceinline__ void ghmc_elem(float L, float& bce, unsigned& bin)
{
    const float kLn2   = 0.6931471805599453f;
    const float kNRLn2 = -1.4426950408889634f;
    const float en  = __builtin_amdgcn_exp2f(kNRLn2 * fabsf(L));  // e^{-|L|}
    const float den = 1.f + en;
    const float lg  = __builtin_amdgcn_logf(den);                 // log2(den)
    const float r   = __builtin_amdgcn_rcpf(den);
    bce = fmaf(lg, kLn2, fmaxf(L, 0.f));                          // softplus(L)
    unsigned babs = (unsigned)(10.f * r);
    babs = babs > 9u ? 9u : babs;                                 // in [5,9]
    bin = (L >= 0.f) ? babs : 9u - babs;
}

// process one float4 chunk (4 consecutive elements of one row) + its rare
// target correction. dt = target col - 4*chunk_col (correction iff 0<=dt<4).
__device__ __forceinline__ void proc4(const float4 v, int dt,
    v2f& a01, v2f& a23, v2f& a45, v2f& a67, v2f& a89,
    unsigned long long& hcnt,
    const v2f C01, const v2f C23, const v2f C45, const v2f C67, const v2f C89)
{
    const float lv[4] = {v.x, v.y, v.z, v.w};
    #pragma unroll
    for (int e = 0; e < 4; ++e) {
        float bce; unsigned bin;
        ghmc_elem(lv[e], bce, bin);
        hcnt += 1ull << (6u * bin);
        const v2f b2 = {bce, bce};
        a01 += __builtin_elementwise_max(b2, C01);
        a23 += __builtin_elementwise_max(b2, C23);
        a45 += __builtin_elementwise_max(b2, C45);
        a67 += __builtin_elementwise_max(b2, C67);
        a89 += __builtin_elementwise_max(b2, C89);
    }
    if (__builtin_expect((unsigned)dt < 4u, 0)) {
        float L = v.x;
        L = (dt == 1) ? v.y : L;
        L = (dt == 2) ? v.z : L;
        L = (dt == 3) ? v.w : L;
        float bn_; unsigned bnb;
        ghmc_elem(L, bn_, bnb);                 // what the main path added
        const float bt_ = bn_ - L;              // softplus(-L) = softplus(L) - L
        const unsigned babs = (bnb >= 5u) ? bnb : 9u - bnb;   // |L|-bin in [5,9]
        const unsigned btb  = (L <= 0.f) ? babs : 9u - babs;
        hcnt += (1ull << (6u * btb)) - (1ull << (6u * bnb));
        const v2f bn2 = {bn_, bn_}, bt2 = {bt_, bt_};
        a01 += __builtin_elementwise_max(bt2, C01) - __builtin_elementwise_max(bn2, C01);
        a23 += __builtin_elementwise_max(bt2, C23) - __builtin_elementwise_max(bn2, C23);
        a45 += __builtin_elementwise_max(bt2, C45) - __builtin_elementwise_max(bn2, C45);
        a67 += __builtin_elementwise_max(bt2, C67) - __builtin_elementwise_max(bn2, C67);
        a89 += __builtin_elementwise_max(bt2, C89) - __builtin_elementwise_max(bn2, C89);
    }
}

__device__ __forceinline__ int dt_for(const int* __restrict__ tgt, int i)
{
    const int row = i / kV4PerRow;                 // magic-mul div (const 250)
    return tgt[row] - (i - row * kV4PerRow) * 4;   // tgt is L1/L2-resident (64 KB)
}

__global__ __launch_bounds__(kThreads) void ghmc_main(
    const float* __restrict__ logits,
    const int* __restrict__ tgt,
    float* __restrict__ pf,
    unsigned* __restrict__ pu)
{
    const v2f C01 = {0.0f,        0.10536052f};
    const v2f C23 = {0.22314355f, 0.35667494f};
    const v2f C45 = {0.51082562f, 0.69314718f};
    const v2f C67 = {0.91629073f, 1.20397280f};
    const v2f C89 = {1.60943791f, 2.30258509f};

    v2f a01 = {0.f,0.f}, a23 = {0.f,0.f}, a45 = {0.f,0.f},
        a67 = {0.f,0.f}, a89 = {0.f,0.f};
    unsigned long long hcnt = 0ull;

    const int gid = blockIdx.x * blockDim.x + threadIdx.x;
    const int n = (kNV4 - 1 - gid) / kS + 1;      // 12 or 13 iterations
    const float4* __restrict__ Lp = reinterpret_cast<const float4*>(logits);

    auto ld = [&](int idx) {                      // clamped (over-read harmless)
        idx = idx < kNV4 ? idx : kNV4 - 1;
        return Lp[idx];
    };

    // modulo-scheduled software pipeline, depth 3-4, unroll-by-4:
    // four NAMED registers used cyclically -> no rotation copies -> no
    // per-iteration vmcnt(0) drain (each load has 3 iters before its use).
    int i = gid;
    float4 q0 = ld(i), q1 = ld(i + kS), q2 = ld(i + 2 * kS);

    int k = 0;
    for (; k + 4 <= n; k += 4) {
        float4 q3 = ld(i + 3 * kS);
        proc4(q0, dt_for(tgt, i),          a01, a23, a45, a67, a89, hcnt, C01, C23, C45, C67, C89);
        q0 = ld(i + 4 * kS);
        proc4(q1, dt_for(tgt, i + kS),     a01, a23, a45, a67, a89, hcnt, C01, C23, C45, C67, C89);
        q1 = ld(i + 5 * kS);
        proc4(q2, dt_for(tgt, i + 2 * kS), a01, a23, a45, a67, a89, hcnt, C01, C23, C45, C67, C89);
        q2 = ld(i + 6 * kS);
        proc4(q3, dt_for(tgt, i + 3 * kS), a01, a23, a45, a67, a89, hcnt, C01, C23, C45, C67, C89);
        i += 4 * kS;
    }
    for (; k < n; ++k) {                          // tail: 0 or 1 iteration
        proc4(q0, dt_for(tgt, i), a01, a23, a45, a67, a89, hcnt, C01, C23, C45, C67, C89);
        q0 = q1; q1 = q2;
        i += kS;
    }

    // expand 6-bit fields -> two u64 with 12-bit fields (wave sum <= 52*64 = 3328 < 4096)
    unsigned long long lo = 0ull, hi = 0ull;
    #pragma unroll
    for (int j = 0; j < 5; ++j) {
        lo += ((hcnt >> (6 * j))       & 63ull) << (12 * j);
        hi += ((hcnt >> (6 * (j + 5))) & 63ull) << (12 * j);
    }
    float r10[10] = {a01.x, a01.y, a23.x, a23.y, a45.x, a45.y, a67.x, a67.y, a89.x, a89.y};
    #pragma unroll
    for (int off = 32; off > 0; off >>= 1) {
        #pragma unroll
        for (int j = 0; j < 10; ++j) r10[j] += __shfl_down(r10[j], off);
        lo += __shfl_down(lo, off);
        hi += __shfl_down(hi, off);
    }

    __shared__ float              sf[4][10];
    __shared__ unsigned long long sc[4][2];
    const int wave = threadIdx.x >> 6;
    const int lane = threadIdx.x & 63;
    if (lane == 0) {
        #pragma unroll
        for (int j = 0; j < 10; ++j) sf[wave][j] = r10[j];
        sc[wave][0] = lo; sc[wave][1] = hi;
    }
    __syncthreads();
    // per-block partials: PLAIN STORES to a private column — zero global atomics
    const int t = threadIdx.x;
    if (t < 10) {
        pf[t * kBlocks + blockIdx.x] = sf[0][t] + sf[1][t] + sf[2][t] + sf[3][t];
    } else if (t < 20) {
        const int b = t - 10;
        const int half = (b < 5) ? 0 : 1;
        const int sh = 12 * (b < 5 ? b : b - 5);
        unsigned s = 0;
        #pragma unroll
        for (int w = 0; w < 4; ++w) s += (unsigned)((sc[w][half] >> sh) & 4095ull);
        pu[b * kBlocks + blockIdx.x] = s;
    }
}

// 10 waves: wave w reduces sum-slot w (f64) and count-slot w (u32), vectorized.
__global__ __launch_bounds__(640) void ghmc_reduce(
    const float* __restrict__ pf,
    const unsigned* __restrict__ pu,
    float* __restrict__ out)
{
    const int wave = threadIdx.x >> 6;
    const int lane = threadIdx.x & 63;

    const float4* pf4 = reinterpret_cast<const float4*>(pf + wave * kBlocks);
    const uint4*  pu4 = reinterpret_cast<const uint4*>(pu + wave * kBlocks);
    double   fs = 0.0;
    unsigned cs = 0u;
    #pragma unroll
    for (int it = 0; it < kBlocks / 256; ++it) {   // 5 float4/uint4 loads per lane
        const float4 f = pf4[lane + it * 64];
        const uint4  u = pu4[lane + it * 64];
        fs += (double)f.x + (double)f.y + (double)f.z + (double)f.w;
        cs += u.x + u.y + u.z + u.w;
    }
    #pragma unroll
    for (int off = 32; off > 0; off >>= 1) {
        fs += __shfl_down(fs, off);
        cs += __shfl_down(cs, off);
    }

    __shared__ double   sF[10];
    __shared__ unsigned sC[10];
    if (lane == 0) { sF[wave] = fs; sC[wave] = cs; }
    __syncthreads();

    if (threadIdx.x == 0) {
        const double cj[10] = {0.0,
            0.10536051565782630, 0.22314355131420976, 0.35667494393873245,
            0.51082562376599072, 0.69314718055994531, 0.91629073187415511,
            1.20397280432593600, 1.60943791243410040, 2.30258509299404570};
        double N[10], cnt[11], cum[11];
        for (int j = 0; j < 10; ++j) N[j] = (double)sC[j];
        cnt[10] = 0.0;
        for (int j = 9; j >= 0; --j) cnt[j] = cnt[j + 1] + N[j];
        cum[10] = 0.0;
        cum[0] = sF[0];                                   // T (c=0 hinge is exact)
        for (int j = 1; j <= 9; ++j)
            cum[j] = sF[j] - cj[j] * ((double)kNElem - cnt[j]);
        double loss = 0.0, n = 0.0;
        for (int j = 0; j < 10; ++j) {
            if (N[j] > 0.0) { n += 1.0; loss += (cum[j] - cum[j + 1]) / N[j]; }
        }
        out[0] = (float)(loss / (n > 1.0 ? n : 1.0));
    }
}

extern "C" void kernel_launch(void* const* d_in, const int* in_sizes, int n_in,
                              void* d_out, int out_size, void* d_ws, size_t ws_size,
                              hipStream_t stream)
{
    const float* logits = (const float*)d_in[0];
    const int*   tgt    = (const int*)d_in[1];
    float*    pf = (float*)d_ws;                                   // 10 x 1280 f32
    unsigned* pu = (unsigned*)((char*)d_ws + 10 * kBlocks * 4);    // 10 x 1280 u32
    ghmc_main<<<kBlocks, kThreads, 0, stream>>>(logits, tgt, pf, pu);
    ghmc_reduce<<<1, 640, 0, stream>>>(pf, pu, (float*)d_out);
}